// Round 1
// baseline (804.838 us; speedup 1.0000x reference)
//
#include <hip/hip_runtime.h>
#include <stdint.h>

// e4m3 fake quantize: out = sign(y) * min(round_rne_3bit_mantissa(|y|), 240) * s,
// y = x / s, with subnormal grid (lsb = 2^-9) below 2^-6.
// Memory-bound elementwise: float4 loads/stores, one vec4 per thread.

__global__ __launch_bounds__(256) void fq_e4m3_kernel(
    const float4* __restrict__ x4,
    const float* __restrict__ scale,
    float4* __restrict__ out4,
    int n4)
{
    int i = blockIdx.x * blockDim.x + threadIdx.x;
    if (i >= n4) return;

    const float s = scale[0];           // uniform scalar load (L2-resident)
    float4 v = x4[i];
    float r[4] = {v.x, v.y, v.z, v.w};

#pragma unroll
    for (int k = 0; k < 4; ++k) {
        // IEEE f32 division to match reference's x/s rounding exactly
        float y = r[k] / s;
        uint32_t u  = __float_as_uint(y);
        uint32_t au = u & 0x7FFFFFFFu;          // |y| bits
        uint32_t sg = u & 0x80000000u;          // sign bit

        // Normal path: RNE-round mantissa to 3 bits (drop low 20 bits),
        // carry propagates into exponent correctly (e.g. 15.9 -> 16).
        uint32_t rn = au + (((au >> 20) & 1u) + 0x0007FFFFu);
        rn &= 0xFFF00000u;
        float qn = fminf(__uint_as_float(rn), 240.0f);

        // Subnormal path (|y| < 2^-6): fixed-point grid lsb = 2^-9.
        // Adding 2^14 places |y| so the f32 mantissa LSB is exactly 2^-9;
        // the add performs the RNE round, the subtract is exact.
        float ay = __uint_as_float(au);
        float qs = (ay + 16384.0f) - 16384.0f;

        float q = (au < 0x3C800000u) ? qs : qn; // 0x3C800000 = 2^-6

        // reapply sign, rescale
        q = __uint_as_float(__float_as_uint(q) | sg);
        r[k] = q * s;
    }

    out4[i] = make_float4(r[0], r[1], r[2], r[3]);
}

extern "C" void kernel_launch(void* const* d_in, const int* in_sizes, int n_in,
                              void* d_out, int out_size, void* d_ws, size_t ws_size,
                              hipStream_t stream) {
    const float* x     = (const float*)d_in[0];
    const float* scale = (const float*)d_in[1];
    float* out         = (float*)d_out;

    int n  = in_sizes[0];        // 8*4096*4096 = 134217728, divisible by 4
    int n4 = n >> 2;
    int block = 256;
    int grid  = (n4 + block - 1) / block;   // 131072 blocks

    fq_e4m3_kernel<<<grid, block, 0, stream>>>(
        (const float4*)x, scale, (float4*)out, n4);
}